// Round 1
// baseline (10616.515 us; speedup 1.0000x reference)
//
#include <hip/hip_runtime.h>
#include <hip/hip_bf16.h>
#include <math.h>

// Problem constants
static constexpr int NX = 32;    // state dim
static constexpr int NU = 8;     // control dim
static constexpr int NA = 24;    // obs dim
static constexpr int NH = 256;   // hidden
static constexpr int NT = 128;   // time steps
static constexpr int NB = 256;   // batch
static constexpr float MINV = 0.01f, MAXV = 1.0f, EPSV = 1e-6f;

// Packed-weight workspace layout (float elements)
static constexpr int LD1 = NH;              // WT1 [32][256]
static constexpr int LDH1 = NX*NX + NX*NU + NX;   // 1024+256+32 = 1312
static constexpr int LDH2 = NA*NX + NA;           // 768+24     = 792
static constexpr size_t OFF_WT1 = 0;                         // 32*256   = 8192
static constexpr size_t OFF_WT2 = OFF_WT1 + (size_t)NX*NH;   // 8192
static constexpr size_t OFF_WH1 = OFF_WT2 + (size_t)NH*NH;   // 73728
static constexpr size_t OFF_WH2 = OFF_WH1 + (size_t)NH*LDH1; // 409600
static constexpr size_t OFF_BH1 = OFF_WH2 + (size_t)NH*LDH2; // 612352
static constexpr size_t OFF_BH2 = OFF_BH1 + LDH1;            // 613664
static constexpr size_t WS_FLOATS = OFF_BH2 + LDH2;          // 614456

// ---------------------------------------------------------------------------
// Pre-pass: transpose src [O][K] row-major -> dst[k*ldd + off + o]
__global__ void pack_transpose(const float* __restrict__ src, float* __restrict__ dst,
                               int O, int K, int ldd, int off)
{
    int idx = blockIdx.x * blockDim.x + threadIdx.x;
    if (idx >= O * K) return;
    int o = idx / K, k = idx - o * K;
    dst[(size_t)k * ldd + off + o] = src[idx];
}

__global__ void pack_bias3(const float* __restrict__ s0, int n0,
                           const float* __restrict__ s1, int n1,
                           const float* __restrict__ s2, int n2,
                           float* __restrict__ dst)
{
    int i = blockIdx.x * blockDim.x + threadIdx.x;
    if (i < n0) dst[i] = s0[i];
    else if (i < n0 + n1) dst[i] = s1[i - n0];
    else if (i < n0 + n1 + n2) dst[i] = s2[i - n0 - n1];
}

// ---------------------------------------------------------------------------
__device__ __forceinline__ void tri_decode(int p, int& l, int& i)
{
    int lo = (int)((sqrtf(8.f * (float)p + 1.f) - 1.f) * 0.5f);
    while ((lo + 1) * (lo + 2) / 2 <= p) lo++;
    while (lo * (lo + 1) / 2 > p) lo--;
    l = lo;
    i = p - lo * (lo + 1) / 2;
}

__device__ __forceinline__ float sigm_scaled(float z)
{
    return MINV + (MAXV - MINV) / (1.f + expf(-z));
}

// shared MLP trunk: h2 = relu(W2 relu(W1 x + b1) + b2). 2 internal syncs.
__device__ __forceinline__ void trunk(const float* __restrict__ WT1,
                                      const float* __restrict__ WT2,
                                      const float* __restrict__ b1,
                                      const float* __restrict__ b2,
                                      const float* xin, float* s_h1, float* s_h2,
                                      int tid)
{
    float acc = b1[tid];
    #pragma unroll
    for (int k = 0; k < NX; k++) acc = fmaf(WT1[k * NH + tid], xin[k], acc);
    s_h1[tid] = fmaxf(acc, 0.f);
    __syncthreads();
    float acc2 = b2[tid];
    #pragma unroll 8
    for (int k = 0; k < NH; k++) acc2 = fmaf(WT2[k * NH + tid], s_h1[k], acc2);
    s_h2[tid] = fmaxf(acc2, 0.f);
    __syncthreads();
}

// ---------------------------------------------------------------------------
__global__ __launch_bounds__(256) void kf_kernel(
    const float* __restrict__ u, const float* __restrict__ a,
    const float* __restrict__ ws,
    const float* __restrict__ b1, const float* __restrict__ b2,
    const float* __restrict__ alpha_p,
    float* __restrict__ out)
{
    const int tid = threadIdx.x;
    const int b   = blockIdx.x;
    const float alpha = alpha_p[0];

    const float* WT1 = ws + OFF_WT1;
    const float* WT2 = ws + OFF_WT2;
    const float* WH1 = ws + OFF_WH1;
    const float* WH2 = ws + OFF_WH2;
    const float* BH1 = ws + OFF_BH1;
    const float* BH2 = ws + OFF_BH2;

    __shared__ float s_h1[NH], s_h2[NH];
    __shared__ float s_Am[NX * NX];
    __shared__ float s_Bm[NX * NU];
    __shared__ float s_nx[NX];
    __shared__ float s_C[NA * NX];
    __shared__ float s_na[NA];
    __shared__ float s_qm[NX], s_qc[NX * NX];
    __shared__ float s_pm[NX], s_pc[NX * NX];
    __shared__ float s_T2[NX * NX];     // Am @ cov
    __shared__ float s_T1[NA * NX];     // C @ cov
    __shared__ float s_aug[2][NA][NA + NX];
    __shared__ float s_innov[NA];
    __shared__ float s_a[NA], s_u[NU];

    const size_t pmO = 0;
    const size_t pcO = (size_t)NT * NB * NX;
    const size_t qmO = pcO + (size_t)NT * NB * NX * NX;
    const size_t qcO = qmO + (size_t)NT * NB * NX;

    for (int t = 0; t < NT; ++t) {
        if (t == 0) {
            // pm0 = 0, pc0 = I
            if (tid < NX) s_pm[tid] = 0.f;
            #pragma unroll
            for (int r = 0; r < 4; r++) {
                int o = tid + 256 * r;
                s_pc[o] = ((o >> 5) == (o & 31)) ? 1.f : 0.f;
            }
            __syncthreads();
        } else {
            // ---------------- prior_step(qm, qc, u[t-1]) -> (pm, pc) --------
            if (tid < NU) s_u[tid] = u[((size_t)(t - 1) * NB + b) * NU + tid];
            trunk(WT1, WT2, b1, b2, s_qm, s_h1, s_h2, tid);

            // heads: Am (I + alpha*M), Bm, nx
            {
                float acc0 = BH1[tid];
                float acc1 = BH1[tid + 256];
                float acc2 = BH1[tid + 512];
                float acc3 = BH1[tid + 768];
                float acc4 = BH1[tid + 1024];
                #pragma unroll 8
                for (int k = 0; k < NH; k++) {
                    float xk = s_h2[k];
                    const float* wr = WH1 + (size_t)k * LDH1 + tid;
                    acc0 = fmaf(wr[0],    xk, acc0);
                    acc1 = fmaf(wr[256],  xk, acc1);
                    acc2 = fmaf(wr[512],  xk, acc2);
                    acc3 = fmaf(wr[768],  xk, acc3);
                    acc4 = fmaf(wr[1024], xk, acc4);
                }
                { int o = tid;       s_Am[o] = (((o>>5)==(o&31)) ? 1.f : 0.f) + alpha * acc0; }
                { int o = tid + 256; s_Am[o] = (((o>>5)==(o&31)) ? 1.f : 0.f) + alpha * acc1; }
                { int o = tid + 512; s_Am[o] = (((o>>5)==(o&31)) ? 1.f : 0.f) + alpha * acc2; }
                { int o = tid + 768; s_Am[o] = (((o>>5)==(o&31)) ? 1.f : 0.f) + alpha * acc3; }
                s_Bm[tid] = acc4;
                if (tid < NX) {
                    float accn = BH1[1280 + tid];
                    #pragma unroll 4
                    for (int k = 0; k < NH; k++)
                        accn = fmaf(WH1[(size_t)k * LDH1 + 1280 + tid], s_h2[k], accn);
                    s_nx[tid] = sigm_scaled(accn);
                }
            }
            __syncthreads();

            // T2 = Am @ qc ; pm = Am@qm + Bm@u
            #pragma unroll
            for (int r = 0; r < 4; r++) {
                int o = tid + 256 * r, i = o >> 5, l = o & 31;
                float acc = 0.f;
                #pragma unroll
                for (int j = 0; j < NX; j++)
                    acc = fmaf(s_Am[i * NX + j], s_qc[j * NX + l], acc);
                s_T2[o] = acc;
            }
            if (tid < NX) {
                float acc = 0.f;
                #pragma unroll
                for (int j = 0; j < NX; j++) acc = fmaf(s_Am[tid * NX + j], s_qm[j], acc);
                #pragma unroll
                for (int j = 0; j < NU; j++) acc = fmaf(s_Bm[tid * NU + j], s_u[j], acc);
                s_pm[tid] = acc;
            }
            __syncthreads();

            // pc = psd(T2 @ Am^T + diag(nx)) — pair-symmetric evaluation
            for (int p = tid; p < NX * (NX + 1) / 2; p += 256) {
                int l, i; tri_decode(p, l, i);
                float a_il = 0.f, a_li = 0.f;
                #pragma unroll
                for (int j = 0; j < NX; j++) {
                    a_il = fmaf(s_T2[i * NX + j], s_Am[l * NX + j], a_il);
                    a_li = fmaf(s_T2[l * NX + j], s_Am[i * NX + j], a_li);
                }
                if (i == l) {
                    s_pc[i * NX + i] = a_il + s_nx[i] + EPSV;
                } else {
                    float v = 0.5f * (a_il + a_li);
                    s_pc[i * NX + l] = v;
                    s_pc[l * NX + i] = v;
                }
            }
            __syncthreads();
        }

        // ---------------- write prior outputs at t; post_step(pm, pc, a[t]) -
        const size_t mIdx = (size_t)t * NB + b;
        if (tid < NX)
            __builtin_nontemporal_store(s_pm[tid], out + pmO + mIdx * NX + tid);
        #pragma unroll
        for (int r = 0; r < 4; r++) {
            int o = tid + 256 * r;
            __builtin_nontemporal_store(s_pc[o], out + pcO + mIdx * NX * NX + o);
        }
        if (tid < NA) s_a[tid] = a[mIdx * NA + tid];

        trunk(WT1, WT2, b1, b2, s_pm, s_h1, s_h2, tid);

        // heads: C, na
        {
            float acc0 = BH2[tid];
            float acc1 = BH2[tid + 256];
            float acc2 = BH2[tid + 512];
            #pragma unroll 8
            for (int k = 0; k < NH; k++) {
                float xk = s_h2[k];
                const float* wr = WH2 + (size_t)k * LDH2 + tid;
                acc0 = fmaf(wr[0],   xk, acc0);
                acc1 = fmaf(wr[256], xk, acc1);
                acc2 = fmaf(wr[512], xk, acc2);
            }
            s_C[tid] = acc0; s_C[tid + 256] = acc1; s_C[tid + 512] = acc2;
            if (tid < NA) {
                float accn = BH2[768 + tid];
                #pragma unroll 4
                for (int k = 0; k < NH; k++)
                    accn = fmaf(WH2[(size_t)k * LDH2 + 768 + tid], s_h2[k], accn);
                s_na[tid] = sigm_scaled(accn);
            }
        }
        __syncthreads();

        // T1 = C @ pc ; innov = a - C@pm
        #pragma unroll
        for (int r = 0; r < 3; r++) {
            int o = tid + 256 * r, i = o >> 5, l = o & 31;
            float acc = 0.f;
            #pragma unroll
            for (int k = 0; k < NX; k++)
                acc = fmaf(s_C[i * NX + k], s_pc[k * NX + l], acc);
            s_T1[o] = acc;
        }
        if (tid < NA) {
            float acc = s_a[tid];
            #pragma unroll
            for (int j = 0; j < NX; j++) acc = fmaf(-s_C[tid * NX + j], s_pm[j], acc);
            s_innov[tid] = acc;
        }
        __syncthreads();

        // build augmented [S | T1], S = T1 @ C^T + diag(na)
        for (int p = tid; p < NA * (NA + 1) / 2; p += 256) {
            int l, i; tri_decode(p, l, i);
            float acc = 0.f;
            #pragma unroll
            for (int j = 0; j < NX; j++)
                acc = fmaf(s_T1[i * NX + j], s_C[l * NX + j], acc);
            if (i == l) acc += s_na[i];
            s_aug[0][i][l] = acc;
            s_aug[0][l][i] = acc;
        }
        for (int p = tid; p < NA * NX; p += 256) {
            int i = p >> 5, j = p & 31;
            s_aug[0][i][NA + j] = s_T1[p];
        }
        __syncthreads();

        // Gauss-Jordan (SPD, no pivoting), ping-pong, 1 barrier per pivot.
        // After 24 pivots result lands in buffer 0: Y = S^-1 (C pc)  [24][32]
        for (int k = 0; k < NA; k++) {
            const float (*src)[NA + NX] = s_aug[k & 1];
            float (*dst)[NA + NX] = s_aug[(k & 1) ^ 1];
            float ipiv = 1.0f / src[k][k];
            for (int p = tid; p < NA * (NA + NX); p += 256) {
                int i = p / (NA + NX), j = p - i * (NA + NX);
                float v;
                if (i == k) v = src[k][j] * ipiv;
                else        v = fmaf(-src[i][k] * ipiv, src[k][j], src[i][j]);
                dst[i][j] = v;
            }
            __syncthreads();
        }

        // qm = pm + Y^T innov ; qc = psd(pc - Y^T T1)
        if (tid < NX) {
            float acc = s_pm[tid];
            #pragma unroll
            for (int i = 0; i < NA; i++)
                acc = fmaf(s_aug[0][i][NA + tid], s_innov[i], acc);
            s_qm[tid] = acc;
        }
        for (int p = tid; p < NX * (NX + 1) / 2; p += 256) {
            int l, i; tri_decode(p, l, i);
            float t_il = 0.f, t_li = 0.f;
            #pragma unroll
            for (int q = 0; q < NA; q++) {
                t_il = fmaf(s_aug[0][q][NA + i], s_T1[q * NX + l], t_il);
                t_li = fmaf(s_aug[0][q][NA + l], s_T1[q * NX + i], t_li);
            }
            if (i == l) {
                s_qc[i * NX + i] = s_pc[i * NX + i] - t_il + EPSV;
            } else {
                float v = 0.5f * ((s_pc[i * NX + l] - t_il) + (s_pc[l * NX + i] - t_li));
                s_qc[i * NX + l] = v;
                s_qc[l * NX + i] = v;
            }
        }
        __syncthreads();

        if (tid < NX)
            __builtin_nontemporal_store(s_qm[tid], out + qmO + mIdx * NX + tid);
        #pragma unroll
        for (int r = 0; r < 4; r++) {
            int o = tid + 256 * r;
            __builtin_nontemporal_store(s_qc[o], out + qcO + mIdx * NX * NX + o);
        }
        // no trailing sync needed: next phase writes only s_h1/s_u (not read here),
        // and s_qm/s_qc aren't rewritten until 20+ barriers later.
    }
}

// ---------------------------------------------------------------------------
extern "C" void kernel_launch(void* const* d_in, const int* in_sizes, int n_in,
                              void* d_out, int out_size, void* d_ws, size_t ws_size,
                              hipStream_t stream)
{
    const float* u    = (const float*)d_in[0];
    const float* a    = (const float*)d_in[1];
    const float* W1   = (const float*)d_in[2];
    const float* b1   = (const float*)d_in[3];
    const float* W2   = (const float*)d_in[4];
    const float* b2   = (const float*)d_in[5];
    const float* WA   = (const float*)d_in[6];
    const float* bA   = (const float*)d_in[7];
    const float* WB   = (const float*)d_in[8];
    const float* bB   = (const float*)d_in[9];
    const float* WC   = (const float*)d_in[10];
    const float* bC   = (const float*)d_in[11];
    const float* Wnx  = (const float*)d_in[12];
    const float* bnx  = (const float*)d_in[13];
    const float* Wna  = (const float*)d_in[14];
    const float* bna  = (const float*)d_in[15];
    const float* alph = (const float*)d_in[16];

    float* ws  = (float*)d_ws;
    float* out = (float*)d_out;

    auto tp = [&](const float* src, int O, int K, float* dstbase, int ldd, int off) {
        int n = O * K;
        pack_transpose<<<(n + 255) / 256, 256, 0, stream>>>(src, dstbase, O, K, ldd, off);
    };
    tp(W1,  NH,      NX, ws + OFF_WT1, LD1, 0);
    tp(W2,  NH,      NH, ws + OFF_WT2, NH,  0);
    tp(WA,  NX * NX, NH, ws + OFF_WH1, LDH1, 0);
    tp(WB,  NX * NU, NH, ws + OFF_WH1, LDH1, NX * NX);
    tp(Wnx, NX,      NH, ws + OFF_WH1, LDH1, NX * NX + NX * NU);
    tp(WC,  NA * NX, NH, ws + OFF_WH2, LDH2, 0);
    tp(Wna, NA,      NH, ws + OFF_WH2, LDH2, NA * NX);

    pack_bias3<<<(LDH1 + 255) / 256, 256, 0, stream>>>(bA, NX * NX, bB, NX * NU, bnx, NX, ws + OFF_BH1);
    pack_bias3<<<(LDH2 + 255) / 256, 256, 0, stream>>>(bC, NA * NX, bna, NA, nullptr, 0, ws + OFF_BH2);

    kf_kernel<<<NB, 256, 0, stream>>>(u, a, ws, b1, b2, alph, out);
}

// Round 3
// 4137.747 us; speedup vs baseline: 2.5658x; 2.5658x over previous
//
#include <hip/hip_runtime.h>
#include <hip/hip_bf16.h>
#include <math.h>

typedef unsigned int uint32;
typedef _Float16 h2_t __attribute__((ext_vector_type(2)));

// Problem constants
static constexpr int NX = 32;    // state dim
static constexpr int NU = 8;     // control dim
static constexpr int NA = 24;    // obs dim
static constexpr int NH = 256;   // hidden
static constexpr int NT = 128;   // time steps
static constexpr int NB = 256;   // batch
static constexpr float MINV = 0.01f, MAXV = 1.0f, EPSV = 1e-6f;

// Padded head widths (outputs)
static constexpr int H1O = NX*NX + NX*NU + NX;   // 1312 real
static constexpr int H1P = 1344;                 // padded
static constexpr int H2O = NA*NX + NA;           // 792 real
static constexpr int H2P = 800;                  // padded

// Workspace layout in uint32 units (all 16B aligned)
static constexpr size_t OFF_W1 = 0;                       // 4 k8 * 256 * 4 = 4096
static constexpr size_t OFF_W2 = 4096;                    // 32*256*4 = 32768
static constexpr size_t OFF_H1 = OFF_W2 + 32768;          // 32*1344*4 = 172032
static constexpr size_t OFF_H2 = OFF_H1 + 172032;         // 32*800*4 = 102400
static constexpr size_t OFF_B1 = OFF_H2 + 102400;         // 1344 floats
static constexpr size_t OFF_B2 = OFF_B1 + 1344;           // 800 floats

// ---------------------------------------------------------------------------
// Pack fp32 weights [O][K] row-major -> fp16 pairs at dst[(k8*LDP + off + o)*4 + q]
// where k = 8*k8 + 2*q (+0/+1 in the low/high half of the uint).
__global__ void pack_half_off(const float* __restrict__ src, uint32* __restrict__ dst,
                              int O, int K, int LDP, int off)
{
    int idx = blockIdx.x * blockDim.x + threadIdx.x;
    int K2 = K >> 1;
    if (idx >= O * K2) return;
    int kk = idx % K2;            // k/2
    int o  = idx / K2;
    int k  = kk * 2;
    int k8 = k >> 3, q = (k >> 1) & 3;
    _Float16 a = (_Float16)src[o * K + k];
    _Float16 b = (_Float16)src[o * K + k + 1];
    uint32 val = (uint32)__builtin_bit_cast(unsigned short, a)
               | ((uint32)__builtin_bit_cast(unsigned short, b) << 16);
    dst[((size_t)k8 * LDP + off + o) * 4 + q] = val;
}

__global__ void pack_bias3(const float* __restrict__ s0, int n0,
                           const float* __restrict__ s1, int n1,
                           const float* __restrict__ s2, int n2,
                           float* __restrict__ dst)
{
    int i = blockIdx.x * blockDim.x + threadIdx.x;
    if (i < n0) dst[i] = s0[i];
    else if (i < n0 + n1) dst[i] = s1[i - n0];
    else if (i < n0 + n1 + n2) dst[i] = s2[i - n0 - n1];
}

// ---------------------------------------------------------------------------
__device__ __forceinline__ float dot2(uint32 w, uint32 x, float acc)
{
#if __has_builtin(__builtin_amdgcn_fdot2)
    return __builtin_amdgcn_fdot2(__builtin_bit_cast(h2_t, w),
                                  __builtin_bit_cast(h2_t, x), acc, false);
#else
    h2_t a = __builtin_bit_cast(h2_t, w), b = __builtin_bit_cast(h2_t, x);
    return acc + (float)a[0] * (float)b[0] + (float)a[1] * (float)b[1];
#endif
}

__device__ __forceinline__ float dot8(uint4 w, uint4 x, float acc)
{
    acc = dot2(w.x, x.x, acc);
    acc = dot2(w.y, x.y, acc);
    acc = dot2(w.z, x.z, acc);
    acc = dot2(w.w, x.w, acc);
    return acc;
}

__device__ __forceinline__ void tri_decode(int p, int& l, int& i)
{
    int lo = (int)((sqrtf(8.f * (float)p + 1.f) - 1.f) * 0.5f);
    while ((lo + 1) * (lo + 2) / 2 <= p) lo++;
    while (lo * (lo + 1) / 2 > p) lo--;
    l = lo;
    i = p - lo * (lo + 1) / 2;
}

__device__ __forceinline__ float sigm_scaled(float z)
{
    return MINV + (MAXV - MINV) / (1.f + expf(-z));
}

__device__ __forceinline__ unsigned short f2h(float v)
{
    _Float16 h = (_Float16)v;
    return __builtin_bit_cast(unsigned short, h);
}

// ---------------------------------------------------------------------------
__global__ __launch_bounds__(512) void kf_kernel(
    const float* __restrict__ u, const float* __restrict__ a,
    const uint32* __restrict__ wsu,
    const float* __restrict__ b1, const float* __restrict__ b2,
    const float* __restrict__ alpha_p,
    float* __restrict__ out)
{
    const int tid = threadIdx.x;
    const int b   = blockIdx.x;
    const float alpha = alpha_p[0];

    const uint4* W1h = (const uint4*)(wsu + OFF_W1);
    const uint4* W2h = (const uint4*)(wsu + OFF_W2);
    const uint4* H1h = (const uint4*)(wsu + OFF_H1);
    const uint4* H2h = (const uint4*)(wsu + OFF_H2);
    const float* BH1 = (const float*)(wsu + OFF_B1);
    const float* BH2 = (const float*)(wsu + OFF_B2);

    __shared__ alignas(16) uint32 s_h1h[NH / 2];
    __shared__ alignas(16) uint32 s_h2h[NH / 2];
    __shared__ alignas(16) uint32 s_qmh[NX / 2];
    __shared__ alignas(16) uint32 s_pmh[NX / 2];
    __shared__ float s_part[2][NH];
    __shared__ float s_Am[NX * NX];
    __shared__ float s_Bm[NX * NU];
    __shared__ float s_nx[NX];
    __shared__ float s_C[NA * NX];
    __shared__ float s_na[NA];
    __shared__ float s_qm[NX], s_qc[NX * NX];
    __shared__ float s_pm[NX], s_pc[NX * NX];
    __shared__ float s_T2[NX * NX];     // Am @ qc
    __shared__ float s_T1[NA * NX];     // C @ pc
    __shared__ float s_S[NA * NA];
    __shared__ float s_Y[NA * NX];      // S^-1 (C pc)
    __shared__ float s_innov[NA];
    __shared__ float s_a[NA], s_u[NU];

    const size_t pmO = 0;
    const size_t pcO = (size_t)NT * NB * NX;
    const size_t qmO = pcO + (size_t)NT * NB * NX * NX;
    const size_t qcO = qmO + (size_t)NT * NB * NX;

    for (int t = 0; t < NT; ++t) {
        const size_t mIdx = (size_t)t * NB + b;

        if (t == 0) {
            if (tid < NX) s_pm[tid] = 0.f;
            if (tid < NX / 2) s_pmh[tid] = 0u;
            {
                int o = tid;           s_pc[o] = ((o >> 5) == (o & 31)) ? 1.f : 0.f;
                o = tid + 512;         s_pc[o] = ((o >> 5) == (o & 31)) ? 1.f : 0.f;
            }
            __syncthreads();
        } else {
            // ===== A1: trunk-W1 on qm  ||  store prev qm/qc, load u[t-1] =====
            if (tid < NH) {
                const uint4* xh = (const uint4*)s_qmh;
                float acc = b1[tid];
                #pragma unroll
                for (int k8 = 0; k8 < 4; k8++)
                    acc = dot8(W1h[k8 * NH + tid], xh[k8], acc);
                float v = fmaxf(acc, 0.f);
                unsigned short us = f2h(v);
                int pi = __shfl_xor((int)us, 1);
                if ((tid & 1) == 0)
                    s_h1h[tid >> 1] = (uint32)us | ((uint32)pi << 16);
            } else {
                const size_t mPrev = (size_t)(t - 1) * NB + b;
                for (int s = tid - 256; s < NX + NX * NX; s += 256) {
                    if (s < NX)
                        __builtin_nontemporal_store(s_qm[s], out + qmO + mPrev * NX + s);
                    else
                        __builtin_nontemporal_store(s_qc[s - NX], out + qcO + mPrev * NX * NX + (s - NX));
                }
                if (tid - 256 < NU)
                    s_u[tid - 256] = u[((size_t)(t - 1) * NB + b) * NU + (tid - 256)];
            }
            __syncthreads();

            // ===== A2: trunk-W2 split-K partials =====
            {
                int o = tid & 255, g = tid >> 8;
                const uint4* xh = (const uint4*)s_h1h;
                float acc = 0.f;
                #pragma unroll 4
                for (int k8 = g * 16; k8 < g * 16 + 16; k8++)
                    acc = dot8(W2h[k8 * NH + o], xh[k8], acc);
                s_part[g][o] = acc;
            }
            __syncthreads();

            // ===== A3: h2 reduce + relu + pack =====
            if (tid < NH) {
                float v = fmaxf(s_part[0][tid] + s_part[1][tid] + b2[tid], 0.f);
                unsigned short us = f2h(v);
                int pi = __shfl_xor((int)us, 1);
                if ((tid & 1) == 0)
                    s_h2h[tid >> 1] = (uint32)us | ((uint32)pi << 16);
            }
            __syncthreads();

            // ===== A4: head1 (Am | Bm | nx) =====
            {
                const uint4* xh = (const uint4*)s_h2h;
                int o0 = tid, o1 = tid + 512, o2 = tid + 1024;
                float a0 = BH1[o0], a1 = BH1[o1];
                float a2 = (tid < 320) ? BH1[o2] : 0.f;
                #pragma unroll 4
                for (int k8 = 0; k8 < 32; k8++) {
                    uint4 x = xh[k8];
                    a0 = dot8(H1h[k8 * H1P + o0], x, a0);
                    a1 = dot8(H1h[k8 * H1P + o1], x, a1);
                    if (tid < 320) a2 = dot8(H1h[k8 * H1P + o2], x, a2);
                }
                #pragma unroll
                for (int r = 0; r < 3; r++) {
                    int o = (r == 0) ? o0 : (r == 1) ? o1 : o2;
                    float acc = (r == 0) ? a0 : (r == 1) ? a1 : a2;
                    if (r == 2 && tid >= 320) break;
                    if (o < NX * NX) {
                        s_Am[o] = (((o >> 5) == (o & 31)) ? 1.f : 0.f) + alpha * acc;
                    } else if (o < NX * NX + NX * NU) {
                        s_Bm[o - NX * NX] = acc;
                    } else if (o < H1O) {
                        s_nx[o - (NX * NX + NX * NU)] = sigm_scaled(acc);
                    }
                }
            }
            __syncthreads();

            // ===== A5: T2 = Am@qc ; pm = Am@qm + Bm@u (+pack) =====
            #pragma unroll
            for (int r = 0; r < 2; r++) {
                int o = tid + 512 * r, i = o >> 5, l = o & 31;
                float acc = 0.f;
                #pragma unroll
                for (int j = 0; j < NX; j++)
                    acc = fmaf(s_Am[i * NX + j], s_qc[j * NX + l], acc);
                s_T2[o] = acc;
            }
            if (tid < NX) {
                float acc = 0.f;
                #pragma unroll
                for (int j = 0; j < NX; j++) acc = fmaf(s_Am[tid * NX + j], s_qm[j], acc);
                #pragma unroll
                for (int j = 0; j < NU; j++) acc = fmaf(s_Bm[tid * NU + j], s_u[j], acc);
                s_pm[tid] = acc;
                unsigned short us = f2h(acc);
                int pi = __shfl_xor((int)us, 1);
                if ((tid & 1) == 0)
                    s_pmh[tid >> 1] = (uint32)us | ((uint32)pi << 16);
            }
            __syncthreads();

            // ===== A6: pc = psd(T2 @ Am^T + diag(nx)) — 528 items, stride 512 =====
            for (int p = tid; p < NX * (NX + 1) / 2; p += 512) {
                int l, i; tri_decode(p, l, i);
                float a_il = 0.f, a_li = 0.f;
                #pragma unroll
                for (int j = 0; j < NX; j++) {
                    a_il = fmaf(s_T2[i * NX + j], s_Am[l * NX + j], a_il);
                    a_li = fmaf(s_T2[l * NX + j], s_Am[i * NX + j], a_li);
                }
                if (i == l) {
                    s_pc[i * NX + i] = a_il + s_nx[i] + EPSV;
                } else {
                    float v = 0.5f * (a_il + a_li);
                    s_pc[i * NX + l] = v;
                    s_pc[l * NX + i] = v;
                }
            }
            __syncthreads();
        }

        // ===== B1: trunk-W1 on pm  ||  store pm/pc, load a[t] =====
        if (tid < NH) {
            const uint4* xh = (const uint4*)s_pmh;
            float acc = b1[tid];
            #pragma unroll
            for (int k8 = 0; k8 < 4; k8++)
                acc = dot8(W1h[k8 * NH + tid], xh[k8], acc);
            float v = fmaxf(acc, 0.f);
            unsigned short us = f2h(v);
            int pi = __shfl_xor((int)us, 1);
            if ((tid & 1) == 0)
                s_h1h[tid >> 1] = (uint32)us | ((uint32)pi << 16);
        } else {
            for (int s = tid - 256; s < NX + NX * NX; s += 256) {
                if (s < NX)
                    __builtin_nontemporal_store(s_pm[s], out + pmO + mIdx * NX + s);
                else
                    __builtin_nontemporal_store(s_pc[s - NX], out + pcO + mIdx * NX * NX + (s - NX));
            }
            if (tid - 256 < NA)
                s_a[tid - 256] = a[mIdx * NA + (tid - 256)];
        }
        __syncthreads();

        // ===== B2: trunk-W2 split-K partials =====
        {
            int o = tid & 255, g = tid >> 8;
            const uint4* xh = (const uint4*)s_h1h;
            float acc = 0.f;
            #pragma unroll 4
            for (int k8 = g * 16; k8 < g * 16 + 16; k8++)
                acc = dot8(W2h[k8 * NH + o], xh[k8], acc);
            s_part[g][o] = acc;
        }
        __syncthreads();

        // ===== B3: h2 reduce + relu + pack =====
        if (tid < NH) {
            float v = fmaxf(s_part[0][tid] + s_part[1][tid] + b2[tid], 0.f);
            unsigned short us = f2h(v);
            int pi = __shfl_xor((int)us, 1);
            if ((tid & 1) == 0)
                s_h2h[tid >> 1] = (uint32)us | ((uint32)pi << 16);
        }
        __syncthreads();

        // ===== B4: head2 (C | na) =====
        {
            const uint4* xh = (const uint4*)s_h2h;
            int o0 = tid, o1 = tid + 512;
            float a0 = BH2[o0];
            float a1 = (tid < H2P - 512) ? BH2[o1] : 0.f;
            #pragma unroll 4
            for (int k8 = 0; k8 < 32; k8++) {
                uint4 x = xh[k8];
                a0 = dot8(H2h[k8 * H2P + o0], x, a0);
                if (tid < H2P - 512) a1 = dot8(H2h[k8 * H2P + o1], x, a1);
            }
            if (o0 < NA * NX) s_C[o0] = a0;
            else if (o0 < H2O) s_na[o0 - NA * NX] = sigm_scaled(a0);
            if (tid < H2P - 512) {
                if (o1 < NA * NX) s_C[o1] = a1;
                else if (o1 < H2O) s_na[o1 - NA * NX] = sigm_scaled(a1);
            }
        }
        __syncthreads();

        // ===== B5: T1 = C@pc ; innov = a - C@pm =====
        {
            int p = tid;
            if (p < NA * NX) {
                int i = p >> 5, l = p & 31;
                float acc = 0.f;
                #pragma unroll
                for (int k = 0; k < NX; k++)
                    acc = fmaf(s_C[i * NX + k], s_pc[k * NX + l], acc);
                s_T1[p] = acc;
            }
            int p2 = tid + 512;
            if (p2 < NA * NX) {
                int i = p2 >> 5, l = p2 & 31;
                float acc = 0.f;
                #pragma unroll
                for (int k = 0; k < NX; k++)
                    acc = fmaf(s_C[i * NX + k], s_pc[k * NX + l], acc);
                s_T1[p2] = acc;
            }
            if (tid >= 488) {
                int i = tid - 488;
                float acc = s_a[i];
                #pragma unroll
                for (int j = 0; j < NX; j++)
                    acc = fmaf(-s_C[i * NX + j], s_pm[j], acc);
                s_innov[i] = acc;
            }
        }
        __syncthreads();

        // ===== B6: S = T1 @ C^T + diag(na), symmetric (300 items) =====
        if (tid < NA * (NA + 1) / 2) {
            int l, i; tri_decode(tid, l, i);
            float acc = 0.f;
            #pragma unroll
            for (int j = 0; j < NX; j++)
                acc = fmaf(s_T1[i * NX + j], s_C[l * NX + j], acc);
            if (i == l) acc += s_na[i];
            s_S[i * NA + l] = acc;
            s_S[l * NA + i] = acc;
        }
        __syncthreads();

        // ===== B7: single-wave register Gauss-Jordan: Y = S^-1 T1 =====
        if (tid < 64) {
            const int j = tid;
            float r[NA];
            #pragma unroll
            for (int i = 0; i < NA; i++) {
                float v = 0.f;
                if (j < NA) v = s_S[i * NA + j];
                else if (j < NA + NX) v = s_T1[i * NX + (j - NA)];
                r[i] = v;
            }
            #pragma unroll
            for (int k = 0; k < NA; k++) {
                float piv = __shfl(r[k], k);
                float ip = 1.0f / piv;
                r[k] *= ip;
                #pragma unroll
                for (int i = 0; i < NA; i++) {
                    if (i == k) continue;
                    float f = __shfl(r[i], k);
                    r[i] = fmaf(-f, r[k], r[i]);
                }
            }
            if (j >= NA && j < NA + NX) {
                #pragma unroll
                for (int i = 0; i < NA; i++) s_Y[i * NX + (j - NA)] = r[i];
            }
        }
        __syncthreads();

        // ===== B8: qm = pm + Y^T innov ; qc = psd(pc - Y^T T1) =====
        if (tid < NX) {
            float acc = s_pm[tid];
            #pragma unroll
            for (int i = 0; i < NA; i++)
                acc = fmaf(s_Y[i * NX + tid], s_innov[i], acc);
            s_qm[tid] = acc;
            unsigned short us = f2h(acc);
            int pi = __shfl_xor((int)us, 1);
            if ((tid & 1) == 0)
                s_qmh[tid >> 1] = (uint32)us | ((uint32)pi << 16);
        }
        for (int p = tid; p < NX * (NX + 1) / 2; p += 512) {
            int l, i; tri_decode(p, l, i);
            float t_il = 0.f, t_li = 0.f;
            #pragma unroll
            for (int q = 0; q < NA; q++) {
                t_il = fmaf(s_Y[q * NX + i], s_T1[q * NX + l], t_il);
                t_li = fmaf(s_Y[q * NX + l], s_T1[q * NX + i], t_li);
            }
            if (i == l) {
                s_qc[i * NX + i] = s_pc[i * NX + i] - t_il + EPSV;
            } else {
                float v = 0.5f * ((s_pc[i * NX + l] - t_il) + (s_pc[l * NX + i] - t_li));
                s_qc[i * NX + l] = v;
                s_qc[l * NX + i] = v;
            }
        }
        __syncthreads();
    }

    // Epilogue: store final qm/qc (t = NT-1)
    {
        const size_t mLast = (size_t)(NT - 1) * NB + b;
        for (int s = tid; s < NX + NX * NX; s += 512) {
            if (s < NX)
                __builtin_nontemporal_store(s_qm[s], out + qmO + mLast * NX + s);
            else
                __builtin_nontemporal_store(s_qc[s - NX], out + qcO + mLast * NX * NX + (s - NX));
        }
    }
}

// ---------------------------------------------------------------------------
extern "C" void kernel_launch(void* const* d_in, const int* in_sizes, int n_in,
                              void* d_out, int out_size, void* d_ws, size_t ws_size,
                              hipStream_t stream)
{
    const float* u    = (const float*)d_in[0];
    const float* a    = (const float*)d_in[1];
    const float* W1   = (const float*)d_in[2];
    const float* b1   = (const float*)d_in[3];
    const float* W2   = (const float*)d_in[4];
    const float* b2   = (const float*)d_in[5];
    const float* WA   = (const float*)d_in[6];
    const float* bA   = (const float*)d_in[7];
    const float* WB   = (const float*)d_in[8];
    const float* bB   = (const float*)d_in[9];
    const float* WC   = (const float*)d_in[10];
    const float* bC   = (const float*)d_in[11];
    const float* Wnx  = (const float*)d_in[12];
    const float* bnx  = (const float*)d_in[13];
    const float* Wna  = (const float*)d_in[14];
    const float* bna  = (const float*)d_in[15];
    const float* alph = (const float*)d_in[16];

    uint32* wsu = (uint32*)d_ws;
    float* out = (float*)d_out;

    auto pk = [&](const float* src, int O, int K, size_t dst_off, int LDP, int off) {
        int n = O * (K / 2);
        pack_half_off<<<(n + 255) / 256, 256, 0, stream>>>(src, wsu + dst_off, O, K, LDP, off);
    };
    pk(W1,  NH,      NX, OFF_W1, NH,  0);
    pk(W2,  NH,      NH, OFF_W2, NH,  0);
    pk(WA,  NX * NX, NH, OFF_H1, H1P, 0);
    pk(WB,  NX * NU, NH, OFF_H1, H1P, NX * NX);
    pk(Wnx, NX,      NH, OFF_H1, H1P, NX * NX + NX * NU);
    pk(WC,  NA * NX, NH, OFF_H2, H2P, 0);
    pk(Wna, NA,      NH, OFF_H2, H2P, NA * NX);

    pack_bias3<<<(H1O + 255) / 256, 256, 0, stream>>>(bA, NX * NX, bB, NX * NU, bnx, NX,
                                                      (float*)(wsu + OFF_B1));
    pack_bias3<<<(H2O + 255) / 256, 256, 0, stream>>>(bC, NA * NX, bna, NA, nullptr, 0,
                                                      (float*)(wsu + OFF_B2));

    kf_kernel<<<NB, 512, 0, stream>>>(u, a, wsu, b1, b2, alph, out);
}